// Round 1
// baseline (312.700 us; speedup 1.0000x reference)
//
#include <hip/hip_runtime.h>

// Sparse 3D conv, scatter formulation.
// Input grid D=96, output DO=48 (K=3, S=2, P=1), Cin=32, Cout=64, B=2.
// One wave (64 lanes) per active input voxel; lane == output channel.
// Per-dim stride-2 parity means only 1 or 2 of the 3 taps per dim are valid;
// we enumerate valid (k, out-coord) pairs per dim and loop the <=8 combos.

#define DOUT 48
#define KS 3
#define CIN 32
#define COUT 64

__global__ __launch_bounds__(256) void spconv_scatter_kernel(
    const float* __restrict__ feat,   // [N, CIN]
    const int*   __restrict__ coors,  // [N, 4] (b, z, y, x)
    const float* __restrict__ W,      // [3,3,3,CIN,COUT]
    float*       __restrict__ out,    // [B*DOUT^3, COUT], pre-zeroed
    int N)
{
    const int lane = threadIdx.x & 63;
    const int wave_global = blockIdx.x * (blockDim.x >> 6) + (threadIdx.x >> 6);
    if (wave_global >= N) return;
    // Force wave-uniform voxel index into an SGPR so coords + features
    // scalarize (s_load) — the whole wave works on one voxel.
    const int vi = __builtin_amdgcn_readfirstlane(wave_global);

    const int b = coors[vi * 4 + 0];
    const int z = coors[vi * 4 + 1];
    const int y = coors[vi * 4 + 2];
    const int x = coors[vi * 4 + 3];

    // Wave-uniform feature vector -> SGPRs.
    float fv[CIN];
    const float* fp = feat + (size_t)vi * CIN;
#pragma unroll
    for (int c = 0; c < CIN; ++c) fv[c] = fp[c];

    // Valid (k, out-coord) pairs per dim: kz must satisfy (z+1-kz) % 2 == 0
    // i.e. kz parity == (z+1) parity, and 0 <= (z+1-kz)/2 < DOUT.
    int kzs[2], zos[2], nz = 0;
    int kys[2], yos[2], ny = 0;
    int kxs[2], xos[2], nx = 0;
    for (int k = (z + 1) & 1; k < KS; k += 2) {
        int o = (z + 1 - k) >> 1;
        if (o >= 0 && o < DOUT) { kzs[nz] = k; zos[nz] = o; ++nz; }
    }
    for (int k = (y + 1) & 1; k < KS; k += 2) {
        int o = (y + 1 - k) >> 1;
        if (o >= 0 && o < DOUT) { kys[ny] = k; yos[ny] = o; ++ny; }
    }
    for (int k = (x + 1) & 1; k < KS; k += 2) {
        int o = (x + 1 - k) >> 1;
        if (o >= 0 && o < DOUT) { kxs[nx] = k; xos[nx] = o; ++nx; }
    }

    // All loop bounds are wave-uniform -> no divergence.
    for (int i = 0; i < nz; ++i) {
        for (int j = 0; j < ny; ++j) {
            for (int k = 0; k < nx; ++k) {
                const int widx = ((kzs[i] * KS + kys[j]) * KS + kxs[k]) * (CIN * COUT);
                const int oidx = (((b * DOUT + zos[i]) * DOUT + yos[j]) * DOUT + xos[k]) * COUT;
                const float* wp = W + widx + lane;
                float acc = 0.0f;
#pragma unroll
                for (int c = 0; c < CIN; ++c) {
                    acc += fv[c] * wp[(size_t)c * COUT];  // coalesced 256B/instr across lanes
                }
                atomicAdd(&out[(size_t)oidx + lane], acc);
            }
        }
    }
}

extern "C" void kernel_launch(void* const* d_in, const int* in_sizes, int n_in,
                              void* d_out, int out_size, void* d_ws, size_t ws_size,
                              hipStream_t stream) {
    const float* feat  = (const float*)d_in[0];
    const int*   coors = (const int*)d_in[1];
    // d_in[2] = batch_size scalar (unused: batch comes from coors, layout is fixed)
    const float* W     = (const float*)d_in[3];
    float*       out   = (float*)d_out;

    const int N = in_sizes[0] / CIN;  // 200000

    // Output must start at zero every call (harness poisons with 0xAA).
    hipMemsetAsync(d_out, 0, (size_t)out_size * sizeof(float), stream);

    const int waves_per_block = 256 / 64;
    const int blocks = (N + waves_per_block - 1) / waves_per_block;
    spconv_scatter_kernel<<<blocks, 256, 0, stream>>>(feat, coors, W, out, N);
}

// Round 2
// 241.507 us; speedup vs baseline: 1.2948x; 1.2948x over previous
//
#include <hip/hip_runtime.h>

// Sparse 3D conv, scatter formulation, round 2.
// One wave (64 lanes) per active input voxel; lane == output channel.
// W is pre-converted to bf16 and swizzled into workspace with layout
//   Wsw[offset 0..26][cchunk 0..3][cout 0..63][cmod 0..7]   (bf16)
// so each (combo) filter tile is read with 4 coalesced 1KB dwordx4 loads
// (each lane: 8 bf16 = 8 consecutive c-values for its own cout).

#define DOUT 48
#define KS 3
#define CIN 32
#define COUT 64
#define WELEMS (27 * CIN * COUT)   // 55296

static __device__ __forceinline__ float bf_lo(unsigned u) {
    return __uint_as_float(u << 16);
}
static __device__ __forceinline__ float bf_hi(unsigned u) {
    return __uint_as_float(u & 0xffff0000u);
}

// fp32 -> bf16 (round to nearest even), transpose+swizzle into workspace.
__global__ __launch_bounds__(256) void convert_w_kernel(
    const float* __restrict__ W, unsigned short* __restrict__ Wsw)
{
    int tid = blockIdx.x * blockDim.x + threadIdx.x;
    if (tid >= WELEMS) return;
    int o  = tid >> 11;        // / (CIN*COUT)
    int r  = tid & 2047;
    int c  = r >> 6;           // / COUT
    int co = r & 63;
    unsigned x = __float_as_uint(W[tid]);
    unsigned lsb = (x >> 16) & 1u;
    x += 0x7fffu + lsb;        // RNE
    unsigned short h = (unsigned short)(x >> 16);
    Wsw[(o << 11) + ((c >> 3) << 9) + (co << 3) + (c & 7)] = h;
}

__global__ __launch_bounds__(256) void spconv_scatter_kernel(
    const float*          __restrict__ feat,   // [N, CIN]
    const int*            __restrict__ coors,  // [N, 4] (b, z, y, x)
    const unsigned short* __restrict__ Wsw,    // swizzled bf16 filters
    float*                __restrict__ out,    // [B*DOUT^3, COUT], pre-zeroed
    int N)
{
    const int lane = threadIdx.x & 63;
    const int wave_global = blockIdx.x * (blockDim.x >> 6) + (threadIdx.x >> 6);
    if (wave_global >= N) return;
    // Wave-uniform voxel index -> SGPR; coords + features scalarize.
    const int vi = __builtin_amdgcn_readfirstlane(wave_global);

    const int b = coors[vi * 4 + 0];
    const int z = coors[vi * 4 + 1];
    const int y = coors[vi * 4 + 2];
    const int x = coors[vi * 4 + 3];

    // Wave-uniform feature vector -> SGPRs.
    float fv[CIN];
    const float* fp = feat + (size_t)vi * CIN;
#pragma unroll
    for (int c = 0; c < CIN; ++c) fv[c] = fp[c];

    // Valid (k, out-coord) pairs per dim (stride-2 parity + bounds).
    int kzs[2], zos[2], nz = 0;
    int kys[2], yos[2], ny = 0;
    int kxs[2], xos[2], nx = 0;
    for (int k = (z + 1) & 1; k < KS; k += 2) {
        int o = (z + 1 - k) >> 1;
        if (o >= 0 && o < DOUT) { kzs[nz] = k; zos[nz] = o; ++nz; }
    }
    for (int k = (y + 1) & 1; k < KS; k += 2) {
        int o = (y + 1 - k) >> 1;
        if (o >= 0 && o < DOUT) { kys[ny] = k; yos[ny] = o; ++ny; }
    }
    for (int k = (x + 1) & 1; k < KS; k += 2) {
        int o = (x + 1 - k) >> 1;
        if (o >= 0 && o < DOUT) { kxs[nx] = k; xos[nx] = o; ++nx; }
    }

    // All loop bounds wave-uniform -> no divergence.
    for (int i = 0; i < nz; ++i) {
        for (int j = 0; j < ny; ++j) {
            for (int k = 0; k < nx; ++k) {
                const int off_id = (kzs[i] * KS + kys[j]) * KS + kxs[k];
                const int oidx = (((b * DOUT + zos[i]) * DOUT + yos[j]) * DOUT + xos[k]) * COUT;
                // Each lane: 4 x dwordx4 (8 bf16 each) = its cout's 32 c-weights.
                const unsigned short* wp = Wsw + (off_id << 11) + (lane << 3);
                float acc = 0.0f;
#pragma unroll
                for (int q = 0; q < 4; ++q) {
                    const uint4 u = *(const uint4*)(wp + (q << 9));
                    const float* f = &fv[q << 3];
                    acc += f[0] * bf_lo(u.x) + f[1] * bf_hi(u.x)
                         + f[2] * bf_lo(u.y) + f[3] * bf_hi(u.y)
                         + f[4] * bf_lo(u.z) + f[5] * bf_hi(u.z)
                         + f[6] * bf_lo(u.w) + f[7] * bf_hi(u.w);
                }
                atomicAdd(&out[(size_t)oidx + lane], acc);
            }
        }
    }
}

extern "C" void kernel_launch(void* const* d_in, const int* in_sizes, int n_in,
                              void* d_out, int out_size, void* d_ws, size_t ws_size,
                              hipStream_t stream) {
    const float* feat  = (const float*)d_in[0];
    const int*   coors = (const int*)d_in[1];
    const float* W     = (const float*)d_in[3];
    float*       out   = (float*)d_out;
    unsigned short* Wsw = (unsigned short*)d_ws;   // 110592 B needed

    const int N = in_sizes[0] / CIN;  // 200000

    // Output must start at zero every call (harness poisons with 0xAA).
    hipMemsetAsync(d_out, 0, (size_t)out_size * sizeof(float), stream);

    convert_w_kernel<<<(WELEMS + 255) / 256, 256, 0, stream>>>(W, Wsw);

    const int waves_per_block = 256 / 64;
    const int blocks = (N + waves_per_block - 1) / waves_per_block;
    spconv_scatter_kernel<<<blocks, 256, 0, stream>>>(feat, coors, Wsw, out, N);
}